// Round 8
// baseline (151.375 us; speedup 1.0000x reference)
//
#include <hip/hip_runtime.h>
#include <hip/hip_bf16.h>
#include <math.h>

// Problem constants
#define DIM   512
#define NTR   16384
#define NT    8192
#define NCLS  16
#define NROWS (NTR + NT)   // 24576 projection rows

// simmain tiling: wave owns a 16-i tile; block = 4 waves = 64 i's, one j-chunk.
#define JS     32                  // j-splits (4096 blocks -> 16 blocks/CU)
#define JC     (NTR / JS)          // 512 j per chunk
#define STEPS  (JC / 32)           // 16 K-steps (32 j each) per wave
#define NSTEPS (NTR / 32)          // 512 global K-steps

#define PROJ_BLOCKS (NROWS / 16)          // 1536 (16 rows/block, 4/wave)
#define PREP_BLOCKS ((NSTEPS * 64) / 256) // 128 (y-bake + accumulator zeroing)

// ws layout (floats): kq [24576][2] | numer [8192][16] | denom [8192] |
//                     yfh | yfl (bf16 A-frag planes)
#define WS_KQ_F    (NROWS * 2)           // 49152
#define WS_NUMER_F (NT * NCLS)           // 131072
#define WS_DENOM_F (NT)                  // 8192
#define WS_ZERO_V4 ((WS_NUMER_F + WS_DENOM_F) / 4)   // 34816 float4s

typedef __attribute__((ext_vector_type(8))) short short8;
typedef __attribute__((ext_vector_type(4))) float f32x4;
typedef __attribute__((ext_vector_type(4))) unsigned int uint4v;

static __device__ __forceinline__ short f2bf(float f) {   // RNE (prep only)
    unsigned u = __float_as_uint(f);
    return (short)((u + 0x7FFFu + ((u >> 16) & 1u)) >> 16);
}
static __device__ __forceinline__ float bf2f(short h) {
    return __uint_as_float(((unsigned)(unsigned short)h) << 16);
}
// Pack 2 positive floats to bf16x2 (round-half-up): 2 adds + 1 v_perm.
static __device__ __forceinline__ unsigned pkbf(float a, float b) {
    unsigned ua = __float_as_uint(a) + 0x8000u;
    unsigned ub = __float_as_uint(b) + 0x8000u;
    return __builtin_amdgcn_perm(ub, ua, 0x07060302);   // (bf(b)<<16)|bf(a)
}

// ---------------------------------------------------------------------------
// Kernel 1 (fused prep): blocks [0,1536) = projection (4 rows/wave, 8
// independent loads + 8 parallel shuffle-reduce chains); blocks [1536,1664) =
// ytr^T bf16 hi/lo bake in MFMA A-frag order + zeroing of numer/denom.
// NO cross-block fences anywhere (round 6: device-scope fences cost ~full-
// L2-writeback per block on multi-XCD CDNA4).
// ---------------------------------------------------------------------------
__global__ __launch_bounds__(256) void prep_kernel(
    const float* __restrict__ xtr, const float* __restrict__ xt,
    const float* __restrict__ A, const float* __restrict__ ytr,
    float* __restrict__ kq, short* __restrict__ yfh,
    short* __restrict__ yfl, float* __restrict__ zbase)
{
    const int b = blockIdx.x;
    if (b < PROJ_BLOCKS) {
        const int wave = threadIdx.x >> 6;
        const int lane = threadIdx.x & 63;
        const int row0 = b * 16 + wave * 4;

        const float* xp[4];
#pragma unroll
        for (int r = 0; r < 4; ++r) {
            const int row = row0 + r;
            xp[r] = (row < NTR) ? (xtr + (size_t)row * DIM)
                                : (xt + (size_t)(row - NTR) * DIM);
        }
        float a0[4] = {0.f, 0.f, 0.f, 0.f}, a1[4] = {0.f, 0.f, 0.f, 0.f};
#pragma unroll
        for (int t = 0; t < 2; ++t) {
            const int d = lane * 4 + t * 256;
            float4 A0 = *(const float4*)(A + 2 * d);       // A[d..d+1][0..1]
            float4 A1 = *(const float4*)(A + 2 * d + 4);   // A[d+2..d+3][0..1]
#pragma unroll
            for (int r = 0; r < 4; ++r) {
                float4 u = *(const float4*)(xp[r] + d);
                a0[r] += u.x * A0.x + u.y * A0.z + u.z * A1.x + u.w * A1.z;
                a1[r] += u.x * A0.y + u.y * A0.w + u.z * A1.y + u.w * A1.w;
            }
        }
#pragma unroll
        for (int off = 32; off >= 1; off >>= 1) {
#pragma unroll
            for (int r = 0; r < 4; ++r) {
                a0[r] += __shfl_xor(a0[r], off, 64);
                a1[r] += __shfl_xor(a1[r], off, 64);
            }
        }
        if (lane == 0) {
            *(float4*)(kq + row0 * 2)     = make_float4(a0[0], a1[0], a0[1], a1[1]);
            *(float4*)(kq + row0 * 2 + 4) = make_float4(a0[2], a1[2], a0[3], a1[3]);
        }
    } else {
        const int idx = (b - PROJ_BLOCKS) * 256 + threadIdx.x;  // 0..32767
        // zero numer+denom (34816 float4s over 32768 threads)
        float4 z = make_float4(0.f, 0.f, 0.f, 0.f);
        for (int p = idx; p < WS_ZERO_V4; p += PREP_BLOCKS * 256)
            ((float4*)zbase)[p] = z;

        const int l   = idx & 63;
        const int s   = idx >> 6;
        const int cls = l & 15;
        const int jb  = s * 32 + (l >> 4) * 8;
        short8 hi, lo;
#pragma unroll
        for (int t = 0; t < 8; ++t) {
            float v = ytr[(size_t)(jb + t) * NCLS + cls];
            short h = f2bf(v);
            hi[t] = h;
            lo[t] = f2bf(v - bf2f(h));
        }
        ((short8*)yfh)[idx] = hi;
        ((short8*)yfl)[idx] = lo;
    }
}

// ---------------------------------------------------------------------------
// Kernel 2: main. Grid (NT/64, JS) = (128, 32) = 4096 blocks (16 blocks/CU,
// oversubscribed). Wave owns a 16-i tile; block stages its 512-j k-chunk
// (fp32, 4 KB) in LDS once; no barriers in the K-loop.
// K-loop is explicitly software-pipelined one step ahead on the GLOBAL
// y-fragment loads (round 7: VGPR=32 showed the allocator couldn't hold any
// loads in flight -> each step ate full L2+LDS latency). launch_bounds
// (256,8) caps VGPRs at 64 (still 8 waves/SIMD) while giving the allocator
// room to hoist the ds_reads too.
// Per K-step (16i x 32j): 8 raw v_exp_f32 -> v_perm bf16 pack -> 3 MFMAs
// (Yhi@E + Ylo@E -> numer, Ones@E -> denom). Fire-and-forget atomic flush;
// separate finalize kernel (round 6: fused-fence variant = +117 us stall).
// ---------------------------------------------------------------------------
__global__ __launch_bounds__(256, 8) void simmain_kernel(
    const float* __restrict__ kq, const short* __restrict__ yfh,
    const short* __restrict__ yfl, float* __restrict__ numer,
    float* __restrict__ denom)
{
    __shared__ float ks[JC * 2];   // 512 float2 = 4 KB, fp32 k-chunk

    const int tid  = threadIdx.x;
    const int wave = tid >> 6;
    const int lane = tid & 63;
    const int j0   = blockIdx.y * JC;

    const int i0   = (blockIdx.x * 4 + wave) * 16;
    const int m    = lane & 15;
    const int quad = lane >> 4;

    // q load first (overlaps the k-staging latency)
    const float2 qv = *(const float2*)(kq + 2 * (NTR + i0 + m));
    const float q0 = qv.x * 1.4426950408889634f;   // pre-scale by log2(e)
    const float q1 = qv.y * 1.4426950408889634f;

    {   // stage k chunk: 1024 floats, 1 float4 per thread, coalesced
        ((float4*)ks)[tid] = ((const float4*)(kq + 2 * j0))[tid];
    }
    __syncthreads();

    f32x4 acc  = {0.f, 0.f, 0.f, 0.f};
    f32x4 acc2 = {0.f, 0.f, 0.f, 0.f};
    short8 ones;
#pragma unroll
    for (int t = 0; t < 8; ++t) ones[t] = (short)0x3F80;   // bf16 1.0

    const short8* __restrict__ yhp = ((const short8*)yfh) + (size_t)blockIdx.y * (STEPS * 64) + lane;
    const short8* __restrict__ ylp = ((const short8*)yfl) + (size_t)blockIdx.y * (STEPS * 64) + lane;
    const float4* __restrict__ kx  = ((const float4*)ks) + quad * 4;   // quad's j-octet

    // ---- software pipeline: y-frags for step 0 in flight before the loop
    short8 yh = yhp[0];
    short8 yl = ylp[0];

#pragma unroll 4
    for (int s = 0; s < STEPS; ++s) {
        // prefetch next step's y-frags (clamped index: last iter reloads s,
        // branch-free, result discarded)
        const int sn = (s + 1 < STEPS) ? (s + 1) : s;
        const short8 yhn = yhp[sn * 64];
        const short8 yln = ylp[sn * 64];

        const float4* kp = kx + s * 16;         // quad-broadcast b128 reads
        const float4 ka = kp[0], kb = kp[1], kc = kp[2], kd = kp[3];

        const float e0 = __builtin_amdgcn_exp2f(fmaf(q1, ka.y, q0 * ka.x));
        const float e1 = __builtin_amdgcn_exp2f(fmaf(q1, ka.w, q0 * ka.z));
        const float e2 = __builtin_amdgcn_exp2f(fmaf(q1, kb.y, q0 * kb.x));
        const float e3 = __builtin_amdgcn_exp2f(fmaf(q1, kb.w, q0 * kb.z));
        const float e4 = __builtin_amdgcn_exp2f(fmaf(q1, kc.y, q0 * kc.x));
        const float e5 = __builtin_amdgcn_exp2f(fmaf(q1, kc.w, q0 * kc.z));
        const float e6 = __builtin_amdgcn_exp2f(fmaf(q1, kd.y, q0 * kd.x));
        const float e7 = __builtin_amdgcn_exp2f(fmaf(q1, kd.w, q0 * kd.z));

        uint4v ep;
        ep[0] = pkbf(e0, e1); ep[1] = pkbf(e2, e3);
        ep[2] = pkbf(e4, e5); ep[3] = pkbf(e6, e7);
        const short8 eb = __builtin_bit_cast(short8, ep);

        acc  = __builtin_amdgcn_mfma_f32_16x16x32_bf16(yh,   eb, acc,  0, 0, 0);
        acc  = __builtin_amdgcn_mfma_f32_16x16x32_bf16(yl,   eb, acc,  0, 0, 0);
        acc2 = __builtin_amdgcn_mfma_f32_16x16x32_bf16(ones, eb, acc2, 0, 0, 0);

        yh = yhn;
        yl = yln;
    }

    // Flush: lane holds numer[i0+m][quad*4+r] = acc[r]; dsum(i0+m) = acc2[*]
    float* nrow = numer + (size_t)(i0 + m) * NCLS + quad * 4;
#pragma unroll
    for (int r = 0; r < 4; ++r)
        atomicAdd(nrow + r, acc[r]);
    if (quad == 0)
        atomicAdd(denom + i0 + m, acc2[0]);
}

// ---------------------------------------------------------------------------
// Kernel 3: finalize — divide numerators by softmax denominator.
// ---------------------------------------------------------------------------
__global__ __launch_bounds__(256) void finalize_kernel(
    const float* __restrict__ numer, const float* __restrict__ denom,
    float* __restrict__ out)
{
    const int idx = blockIdx.x * 256 + threadIdx.x;   // < NT*NCLS
    out[idx] = numer[idx] / denom[idx >> 4];
}

// ---------------------------------------------------------------------------
extern "C" void kernel_launch(void* const* d_in, const int* in_sizes, int n_in,
                              void* d_out, int out_size, void* d_ws, size_t ws_size,
                              hipStream_t stream)
{
    const float* xtr = (const float*)d_in[0];   // [16384][512]
    const float* ytr = (const float*)d_in[1];   // [16384][16]
    const float* xt  = (const float*)d_in[2];   // [8192][512]
    const float* A   = (const float*)d_in[3];   // [512][2]
    float* out = (float*)d_out;                 // [8192][16]

    float* kq    = (float*)d_ws;                       // 49152 floats
    float* numer = kq + WS_KQ_F;                       // 131072 floats
    float* denom = numer + WS_NUMER_F;                 // 8192 floats
    short* yfh   = (short*)(denom + WS_DENOM_F);       // 262144 shorts (512 KB)
    short* yfl   = yfh + NSTEPS * 64 * 8;              // 262144 shorts (512 KB)

    prep_kernel<<<PROJ_BLOCKS + PREP_BLOCKS, 256, 0, stream>>>(
        xtr, xt, A, ytr, kq, yfh, yfl, numer);
    simmain_kernel<<<dim3(NT / 64, JS), 256, 0, stream>>>(
        kq, yfh, yfl, numer, denom);
    finalize_kernel<<<(NT * NCLS) / 256, 256, 0, stream>>>(numer, denom, out);
}

// Round 9
// 130.638 us; speedup vs baseline: 1.1587x; 1.1587x over previous
//
#include <hip/hip_runtime.h>
#include <hip/hip_bf16.h>
#include <math.h>

// Problem constants
#define DIM   512
#define NTR   16384
#define NT    8192
#define NCLS  16
#define NROWS (NTR + NT)   // 24576 projection rows

// simmain tiling: wave owns TWO 16-i tiles (IT=2); block = 4 waves = 128 i's.
// Grid (NT/128, JS) = (64, 16) = 1024 blocks = 4 blocks/CU x 4 waves.
#define JS     16                  // j-splits
#define JC     (NTR / JS)          // 1024 j per chunk
#define STEPS  (JC / 32)           // 32 K-steps (32 j each) per wave
#define NSTEPS (NTR / 32)          // 512 global K-steps

#define PROJ_BLOCKS (NROWS / 16)          // 1536 (16 rows/block, 4/wave)
#define PREP_BLOCKS ((NSTEPS * 64) / 256) // 128 (y-bake + accumulator zeroing)

// ws layout (floats): kq [24576][2] | numer [8192][16] | denom [8192] |
//                     yfh | yfl (bf16 A-frag planes)
#define WS_KQ_F    (NROWS * 2)           // 49152
#define WS_NUMER_F (NT * NCLS)           // 131072
#define WS_DENOM_F (NT)                  // 8192
#define WS_ZERO_V4 ((WS_NUMER_F + WS_DENOM_F) / 4)   // 34816 float4s

typedef __attribute__((ext_vector_type(8))) short short8;
typedef __attribute__((ext_vector_type(4))) float f32x4;
typedef __attribute__((ext_vector_type(4))) unsigned int uint4v;

static __device__ __forceinline__ short f2bf(float f) {   // RNE (prep only)
    unsigned u = __float_as_uint(f);
    return (short)((u + 0x7FFFu + ((u >> 16) & 1u)) >> 16);
}
static __device__ __forceinline__ float bf2f(short h) {
    return __uint_as_float(((unsigned)(unsigned short)h) << 16);
}
// Pack 2 positive floats to bf16x2 (round-half-up): 2 adds + 1 v_perm.
static __device__ __forceinline__ unsigned pkbf(float a, float b) {
    unsigned ua = __float_as_uint(a) + 0x8000u;
    unsigned ub = __float_as_uint(b) + 0x8000u;
    return __builtin_amdgcn_perm(ub, ua, 0x07060302);   // (bf(b)<<16)|bf(a)
}

// ---------------------------------------------------------------------------
// Kernel 1 (fused prep): blocks [0,1536) = projection (4 rows/wave, 8
// independent loads + 8 parallel shuffle-reduce chains); blocks [1536,1664) =
// ytr^T bf16 hi/lo bake in MFMA A-frag order + zeroing of numer/denom.
// NO cross-block fences anywhere (round 6: device-scope fences cost ~full-
// L2-writeback per block on multi-XCD CDNA4).
// ---------------------------------------------------------------------------
__global__ __launch_bounds__(256) void prep_kernel(
    const float* __restrict__ xtr, const float* __restrict__ xt,
    const float* __restrict__ A, const float* __restrict__ ytr,
    float* __restrict__ kq, short* __restrict__ yfh,
    short* __restrict__ yfl, float* __restrict__ zbase)
{
    const int b = blockIdx.x;
    if (b < PROJ_BLOCKS) {
        const int wave = threadIdx.x >> 6;
        const int lane = threadIdx.x & 63;
        const int row0 = b * 16 + wave * 4;

        const float* xp[4];
#pragma unroll
        for (int r = 0; r < 4; ++r) {
            const int row = row0 + r;
            xp[r] = (row < NTR) ? (xtr + (size_t)row * DIM)
                                : (xt + (size_t)(row - NTR) * DIM);
        }
        float a0[4] = {0.f, 0.f, 0.f, 0.f}, a1[4] = {0.f, 0.f, 0.f, 0.f};
#pragma unroll
        for (int t = 0; t < 2; ++t) {
            const int d = lane * 4 + t * 256;
            float4 A0 = *(const float4*)(A + 2 * d);       // A[d..d+1][0..1]
            float4 A1 = *(const float4*)(A + 2 * d + 4);   // A[d+2..d+3][0..1]
#pragma unroll
            for (int r = 0; r < 4; ++r) {
                float4 u = *(const float4*)(xp[r] + d);
                a0[r] += u.x * A0.x + u.y * A0.z + u.z * A1.x + u.w * A1.z;
                a1[r] += u.x * A0.y + u.y * A0.w + u.z * A1.y + u.w * A1.w;
            }
        }
#pragma unroll
        for (int off = 32; off >= 1; off >>= 1) {
#pragma unroll
            for (int r = 0; r < 4; ++r) {
                a0[r] += __shfl_xor(a0[r], off, 64);
                a1[r] += __shfl_xor(a1[r], off, 64);
            }
        }
        if (lane == 0) {
            *(float4*)(kq + row0 * 2)     = make_float4(a0[0], a1[0], a0[1], a1[1]);
            *(float4*)(kq + row0 * 2 + 4) = make_float4(a0[2], a1[2], a0[3], a1[3]);
        }
    } else {
        const int idx = (b - PROJ_BLOCKS) * 256 + threadIdx.x;  // 0..32767
        // zero numer+denom (34816 float4s over 32768 threads)
        float4 z = make_float4(0.f, 0.f, 0.f, 0.f);
        for (int p = idx; p < WS_ZERO_V4; p += PREP_BLOCKS * 256)
            ((float4*)zbase)[p] = z;

        const int l   = idx & 63;
        const int s   = idx >> 6;
        const int cls = l & 15;
        const int jb  = s * 32 + (l >> 4) * 8;
        short8 hi, lo;
#pragma unroll
        for (int t = 0; t < 8; ++t) {
            float v = ytr[(size_t)(jb + t) * NCLS + cls];
            short h = f2bf(v);
            hi[t] = h;
            lo[t] = f2bf(v - bf2f(h));
        }
        ((short8*)yfh)[idx] = hi;
        ((short8*)yfl)[idx] = lo;
    }
}

// ---------------------------------------------------------------------------
// Kernel 2: main. Grid (NT/128, JS) = (64, 16) = 1024 blocks (4 blocks/CU).
// Round-7 skeleton (that config measured 43 us / VALUBusy 48%) + IT=2:
// each wave owns TWO 16-i tiles. The y-fragments (MFMA A-operand) and the
// k ds_reads are SHARED between the tiles, so one y/k fetch now feeds 1024
// pairs (2x round 7) and the wave has 16 independent exp chains of VALU
// (~250 cyc issue/step) to overlap the ~300-400 cyc memory latency -- ILP
// from more work per wave, not from hand-prefetch (round 8 showed the
// allocator undoes that) and not from min-waves launch_bounds (VGPR cap).
// Per K-step (2 x 16i x 32j): 16 raw v_exp_f32 -> 2 bf16 B-frags -> 6 MFMAs.
// Fire-and-forget atomic flush; separate finalize kernel (round 6: fences
// cost ~full-L2-writeback per block).
// ---------------------------------------------------------------------------
__global__ __launch_bounds__(256) void simmain_kernel(
    const float* __restrict__ kq, const short* __restrict__ yfh,
    const short* __restrict__ yfl, float* __restrict__ numer,
    float* __restrict__ denom)
{
    __shared__ float ks[JC * 2];   // 1024 float2 = 8 KB, fp32 k-chunk

    const int tid  = threadIdx.x;
    const int wave = tid >> 6;
    const int lane = tid & 63;
    const int j0   = blockIdx.y * JC;

    {   // stage k chunk: 2048 floats, 2 x float4 per thread, coalesced
        const float4* src = (const float4*)(kq + 2 * j0);
        float4* dst = (float4*)ks;
#pragma unroll
        for (int p = 0; p < (JC * 2 / 4) / 256; ++p)
            dst[tid + 256 * p] = src[tid + 256 * p];
    }
    __syncthreads();

    const int i0   = (blockIdx.x * 8 + wave * 2) * 16;   // tile A; tile B = +16
    const int m    = lane & 15;
    const int quad = lane >> 4;

    // q for both tiles, pre-scaled by log2(e) so e = exp2(logit')
    const float2 qva = *(const float2*)(kq + 2 * (NTR + i0 + m));
    const float2 qvb = *(const float2*)(kq + 2 * (NTR + i0 + 16 + m));
    const float qa0 = qva.x * 1.4426950408889634f;
    const float qa1 = qva.y * 1.4426950408889634f;
    const float qb0 = qvb.x * 1.4426950408889634f;
    const float qb1 = qvb.y * 1.4426950408889634f;

    f32x4 accA  = {0.f, 0.f, 0.f, 0.f};
    f32x4 accA2 = {0.f, 0.f, 0.f, 0.f};
    f32x4 accB  = {0.f, 0.f, 0.f, 0.f};
    f32x4 accB2 = {0.f, 0.f, 0.f, 0.f};
    short8 ones;
#pragma unroll
    for (int t = 0; t < 8; ++t) ones[t] = (short)0x3F80;   // bf16 1.0

    const short8* __restrict__ yhp = ((const short8*)yfh) + (size_t)blockIdx.y * (STEPS * 64) + lane;
    const short8* __restrict__ ylp = ((const short8*)yfl) + (size_t)blockIdx.y * (STEPS * 64) + lane;
    const float4* __restrict__ kx  = ((const float4*)ks) + quad * 4;   // quad's j-octet

#pragma unroll 2
    for (int s = 0; s < STEPS; ++s) {
        const short8 yh = yhp[s * 64];          // coalesced dwordx4, L2-hot
        const short8 yl = ylp[s * 64];          // (shared by both i-tiles)
        const float4* kp = kx + s * 16;         // quad-broadcast b128 reads
        const float4 ka = kp[0], kb = kp[1], kc = kp[2], kd = kp[3];

        // tile A: 8 exps
        const float a0 = __builtin_amdgcn_exp2f(fmaf(qa1, ka.y, qa0 * ka.x));
        const float a1 = __builtin_amdgcn_exp2f(fmaf(qa1, ka.w, qa0 * ka.z));
        const float a2 = __builtin_amdgcn_exp2f(fmaf(qa1, kb.y, qa0 * kb.x));
        const float a3 = __builtin_amdgcn_exp2f(fmaf(qa1, kb.w, qa0 * kb.z));
        const float a4 = __builtin_amdgcn_exp2f(fmaf(qa1, kc.y, qa0 * kc.x));
        const float a5 = __builtin_amdgcn_exp2f(fmaf(qa1, kc.w, qa0 * kc.z));
        const float a6 = __builtin_amdgcn_exp2f(fmaf(qa1, kd.y, qa0 * kd.x));
        const float a7 = __builtin_amdgcn_exp2f(fmaf(qa1, kd.w, qa0 * kd.z));
        // tile B: 8 exps (independent chains)
        const float b0 = __builtin_amdgcn_exp2f(fmaf(qb1, ka.y, qb0 * ka.x));
        const float b1 = __builtin_amdgcn_exp2f(fmaf(qb1, ka.w, qb0 * ka.z));
        const float b2 = __builtin_amdgcn_exp2f(fmaf(qb1, kb.y, qb0 * kb.x));
        const float b3 = __builtin_amdgcn_exp2f(fmaf(qb1, kb.w, qb0 * kb.z));
        const float b4 = __builtin_amdgcn_exp2f(fmaf(qb1, kc.y, qb0 * kc.x));
        const float b5 = __builtin_amdgcn_exp2f(fmaf(qb1, kc.w, qb0 * kc.z));
        const float b6 = __builtin_amdgcn_exp2f(fmaf(qb1, kd.y, qb0 * kd.x));
        const float b7 = __builtin_amdgcn_exp2f(fmaf(qb1, kd.w, qb0 * kd.z));

        uint4v epa, epb;
        epa[0] = pkbf(a0, a1); epa[1] = pkbf(a2, a3);
        epa[2] = pkbf(a4, a5); epa[3] = pkbf(a6, a7);
        epb[0] = pkbf(b0, b1); epb[1] = pkbf(b2, b3);
        epb[2] = pkbf(b4, b5); epb[3] = pkbf(b6, b7);
        const short8 ea = __builtin_bit_cast(short8, epa);
        const short8 eb = __builtin_bit_cast(short8, epb);

        accA  = __builtin_amdgcn_mfma_f32_16x16x32_bf16(yh,   ea, accA,  0, 0, 0);
        accA  = __builtin_amdgcn_mfma_f32_16x16x32_bf16(yl,   ea, accA,  0, 0, 0);
        accA2 = __builtin_amdgcn_mfma_f32_16x16x32_bf16(ones, ea, accA2, 0, 0, 0);
        accB  = __builtin_amdgcn_mfma_f32_16x16x32_bf16(yh,   eb, accB,  0, 0, 0);
        accB  = __builtin_amdgcn_mfma_f32_16x16x32_bf16(yl,   eb, accB,  0, 0, 0);
        accB2 = __builtin_amdgcn_mfma_f32_16x16x32_bf16(ones, eb, accB2, 0, 0, 0);
    }

    // Flush: lane holds numer[i+m][quad*4+r]; D layout col=lane&15, row=quad*4+reg.
    float* nrowA = numer + (size_t)(i0 + m) * NCLS + quad * 4;
    float* nrowB = numer + (size_t)(i0 + 16 + m) * NCLS + quad * 4;
#pragma unroll
    for (int r = 0; r < 4; ++r) {
        atomicAdd(nrowA + r, accA[r]);
        atomicAdd(nrowB + r, accB[r]);
    }
    if (quad == 0) {
        atomicAdd(denom + i0 + m, accA2[0]);
        atomicAdd(denom + i0 + 16 + m, accB2[0]);
    }
}

// ---------------------------------------------------------------------------
// Kernel 3: finalize — divide numerators by softmax denominator.
// ---------------------------------------------------------------------------
__global__ __launch_bounds__(256) void finalize_kernel(
    const float* __restrict__ numer, const float* __restrict__ denom,
    float* __restrict__ out)
{
    const int idx = blockIdx.x * 256 + threadIdx.x;   // < NT*NCLS
    out[idx] = numer[idx] / denom[idx >> 4];
}

// ---------------------------------------------------------------------------
extern "C" void kernel_launch(void* const* d_in, const int* in_sizes, int n_in,
                              void* d_out, int out_size, void* d_ws, size_t ws_size,
                              hipStream_t stream)
{
    const float* xtr = (const float*)d_in[0];   // [16384][512]
    const float* ytr = (const float*)d_in[1];   // [16384][16]
    const float* xt  = (const float*)d_in[2];   // [8192][512]
    const float* A   = (const float*)d_in[3];   // [512][2]
    float* out = (float*)d_out;                 // [8192][16]

    float* kq    = (float*)d_ws;                       // 49152 floats
    float* numer = kq + WS_KQ_F;                       // 131072 floats
    float* denom = numer + WS_NUMER_F;                 // 8192 floats
    short* yfh   = (short*)(denom + WS_DENOM_F);       // 262144 shorts (512 KB)
    short* yfl   = yfh + NSTEPS * 64 * 8;              // 262144 shorts (512 KB)

    prep_kernel<<<PROJ_BLOCKS + PREP_BLOCKS, 256, 0, stream>>>(
        xtr, xt, A, ytr, kq, yfh, yfl, numer);
    simmain_kernel<<<dim3(NT / 128, JS), 256, 0, stream>>>(
        kq, yfh, yfl, numer, denom);
    finalize_kernel<<<(NT * NCLS) / 256, 256, 0, stream>>>(numer, denom, out);
}

// Round 10
// 127.110 us; speedup vs baseline: 1.1909x; 1.0278x over previous
//
#include <hip/hip_runtime.h>
#include <hip/hip_bf16.h>
#include <math.h>

// Problem constants
#define DIM   512
#define NTR   16384
#define NT    8192
#define NCLS  16
#define NROWS (NTR + NT)   // 24576 projection rows

// simmain tiling (round-7 skeleton, measured best 43 us):
// wave owns one 16-i tile; block = 4 waves = 64 i's, one 1024-j chunk.
// Grid (NT/64, JS) = (128, 16) = 2048 blocks = 8 blocks/CU.
#define JS     16                  // j-splits
#define JC     (NTR / JS)          // 1024 j per chunk
#define STEPS  (JC / 32)           // 32 K-steps (32 j each) per wave
#define NSTEPS (NTR / 32)          // 512 global K-steps

#define PROJ_BLOCKS (NROWS / 16)          // 1536 (16 rows/block, 4/wave)
#define PREP_BLOCKS ((NSTEPS * 64) / 256) // 128 (y-bake + accumulator zeroing)

// ws layout (floats): kq [24576][2] | numer [8192][16] | denom [8192] |
//                     yfh | yfl (bf16 A-frag planes)
#define WS_KQ_F    (NROWS * 2)           // 49152
#define WS_NUMER_F (NT * NCLS)           // 131072
#define WS_DENOM_F (NT)                  // 8192
#define WS_ZERO_V4 ((WS_NUMER_F + WS_DENOM_F) / 4)   // 34816 float4s

typedef __attribute__((ext_vector_type(8))) short short8;
typedef __attribute__((ext_vector_type(4))) float f32x4;
typedef __attribute__((ext_vector_type(4))) unsigned int uint4v;

static __device__ __forceinline__ short f2bf(float f) {   // RNE (prep only)
    unsigned u = __float_as_uint(f);
    return (short)((u + 0x7FFFu + ((u >> 16) & 1u)) >> 16);
}
static __device__ __forceinline__ float bf2f(short h) {
    return __uint_as_float(((unsigned)(unsigned short)h) << 16);
}
// Pack 2 positive floats to bf16x2 (round-half-up): 2 adds + 1 v_perm.
static __device__ __forceinline__ unsigned pkbf(float a, float b) {
    unsigned ua = __float_as_uint(a) + 0x8000u;
    unsigned ub = __float_as_uint(b) + 0x8000u;
    return __builtin_amdgcn_perm(ub, ua, 0x07060302);   // (bf(b)<<16)|bf(a)
}

// ---------------------------------------------------------------------------
// Kernel 1 (fused prep): blocks [0,1536) = projection (4 rows/wave, 8
// independent loads + 8 parallel shuffle-reduce chains); blocks [1536,1664) =
// ytr^T bf16 hi/lo bake in MFMA A-frag order + zeroing of numer/denom.
// NO cross-block fences anywhere (round 6: device-scope fences cost ~full-
// L2-writeback per block on multi-XCD CDNA4).
// ---------------------------------------------------------------------------
__global__ __launch_bounds__(256) void prep_kernel(
    const float* __restrict__ xtr, const float* __restrict__ xt,
    const float* __restrict__ A, const float* __restrict__ ytr,
    float* __restrict__ kq, short* __restrict__ yfh,
    short* __restrict__ yfl, float* __restrict__ zbase)
{
    const int b = blockIdx.x;
    if (b < PROJ_BLOCKS) {
        const int wave = threadIdx.x >> 6;
        const int lane = threadIdx.x & 63;
        const int row0 = b * 16 + wave * 4;

        const float* xp[4];
#pragma unroll
        for (int r = 0; r < 4; ++r) {
            const int row = row0 + r;
            xp[r] = (row < NTR) ? (xtr + (size_t)row * DIM)
                                : (xt + (size_t)(row - NTR) * DIM);
        }
        float a0[4] = {0.f, 0.f, 0.f, 0.f}, a1[4] = {0.f, 0.f, 0.f, 0.f};
#pragma unroll
        for (int t = 0; t < 2; ++t) {
            const int d = lane * 4 + t * 256;
            float4 A0 = *(const float4*)(A + 2 * d);       // A[d..d+1][0..1]
            float4 A1 = *(const float4*)(A + 2 * d + 4);   // A[d+2..d+3][0..1]
#pragma unroll
            for (int r = 0; r < 4; ++r) {
                float4 u = *(const float4*)(xp[r] + d);
                a0[r] += u.x * A0.x + u.y * A0.z + u.z * A1.x + u.w * A1.z;
                a1[r] += u.x * A0.y + u.y * A0.w + u.z * A1.y + u.w * A1.w;
            }
        }
#pragma unroll
        for (int off = 32; off >= 1; off >>= 1) {
#pragma unroll
            for (int r = 0; r < 4; ++r) {
                a0[r] += __shfl_xor(a0[r], off, 64);
                a1[r] += __shfl_xor(a1[r], off, 64);
            }
        }
        if (lane == 0) {
            *(float4*)(kq + row0 * 2)     = make_float4(a0[0], a1[0], a0[1], a1[1]);
            *(float4*)(kq + row0 * 2 + 4) = make_float4(a0[2], a1[2], a0[3], a1[3]);
        }
    } else {
        const int idx = (b - PROJ_BLOCKS) * 256 + threadIdx.x;  // 0..32767
        // zero numer+denom (34816 float4s over 32768 threads)
        float4 z = make_float4(0.f, 0.f, 0.f, 0.f);
        for (int p = idx; p < WS_ZERO_V4; p += PREP_BLOCKS * 256)
            ((float4*)zbase)[p] = z;

        const int l   = idx & 63;
        const int s   = idx >> 6;
        const int cls = l & 15;
        const int jb  = s * 32 + (l >> 4) * 8;
        short8 hi, lo;
#pragma unroll
        for (int t = 0; t < 8; ++t) {
            float v = ytr[(size_t)(jb + t) * NCLS + cls];
            short h = f2bf(v);
            hi[t] = h;
            lo[t] = f2bf(v - bf2f(h));
        }
        ((short8*)yfh)[idx] = hi;
        ((short8*)yfl)[idx] = lo;
    }
}

// ---------------------------------------------------------------------------
// Kernel 2: main. Grid (NT/64, JS) = (128, 16) = 2048 blocks (8 blocks/CU) —
// the round-7 config (measured best). ONE change vs round 7: explicit 1-step
// register prefetch of BOTH the y-fragments (global, ~200 cyc L2) and the
// k-octet (LDS, ~120 cyc), written as rotation variables so the dataflow
// places each load one full compute-body ahead of its use. NO min-waves
// launch_bounds (round 8 showed that caps VGPRs and kills the pipeline).
// Per K-step (16i x 32j): 8 raw v_exp_f32 -> v_perm bf16 pack -> 3 MFMAs
// (Yhi@E + Ylo@E -> numer, Ones@E -> denom). Fire-and-forget atomic flush;
// separate finalize kernel (round 6: fences = ~full-L2-writeback per block).
// ---------------------------------------------------------------------------
__global__ __launch_bounds__(256) void simmain_kernel(
    const float* __restrict__ kq, const short* __restrict__ yfh,
    const short* __restrict__ yfl, float* __restrict__ numer,
    float* __restrict__ denom)
{
    __shared__ float ks[JC * 2];   // 1024 float2 = 8 KB, fp32 k-chunk

    const int tid  = threadIdx.x;
    const int wave = tid >> 6;
    const int lane = tid & 63;
    const int j0   = blockIdx.y * JC;

    const int i0   = (blockIdx.x * 4 + wave) * 16;
    const int m    = lane & 15;
    const int quad = lane >> 4;

    // q load first (overlaps k-staging latency)
    const float2 qv = *(const float2*)(kq + 2 * (NTR + i0 + m));
    const float q0 = qv.x * 1.4426950408889634f;   // pre-scale by log2(e)
    const float q1 = qv.y * 1.4426950408889634f;

    {   // stage k chunk: 2048 floats, 2 x float4 per thread, coalesced
        const float4* src = (const float4*)(kq + 2 * j0);
        float4* dst = (float4*)ks;
#pragma unroll
        for (int p = 0; p < (JC * 2 / 4) / 256; ++p)
            dst[tid + 256 * p] = src[tid + 256 * p];
    }
    __syncthreads();

    f32x4 acc  = {0.f, 0.f, 0.f, 0.f};
    f32x4 acc2 = {0.f, 0.f, 0.f, 0.f};
    short8 ones;
#pragma unroll
    for (int t = 0; t < 8; ++t) ones[t] = (short)0x3F80;   // bf16 1.0

    const short8* __restrict__ yhp = ((const short8*)yfh) + (size_t)blockIdx.y * (STEPS * 64) + lane;
    const short8* __restrict__ ylp = ((const short8*)yfl) + (size_t)blockIdx.y * (STEPS * 64) + lane;
    const float4* __restrict__ kx  = ((const float4*)ks) + quad * 4;   // quad's j-octet

    // ---- 1-deep pipeline: step-0 operands in flight before the loop
    short8 yh = yhp[0];
    short8 yl = ylp[0];
    float4 ka = kx[0], kb = kx[1], kc = kx[2], kd = kx[3];

#pragma unroll 4
    for (int s = 0; s < STEPS; ++s) {
        // issue next step's loads FIRST (clamped on last iter, branch-free)
        const int sn = (s + 1 < STEPS) ? (s + 1) : s;
        const short8 yhn = yhp[sn * 64];
        const short8 yln = ylp[sn * 64];
        const float4* kpn = kx + sn * 16;
        const float4 kan = kpn[0], kbn = kpn[1], kcn = kpn[2], kdn = kpn[3];

        // compute current step from registers loaded one body ago
        const float e0 = __builtin_amdgcn_exp2f(fmaf(q1, ka.y, q0 * ka.x));
        const float e1 = __builtin_amdgcn_exp2f(fmaf(q1, ka.w, q0 * ka.z));
        const float e2 = __builtin_amdgcn_exp2f(fmaf(q1, kb.y, q0 * kb.x));
        const float e3 = __builtin_amdgcn_exp2f(fmaf(q1, kb.w, q0 * kb.z));
        const float e4 = __builtin_amdgcn_exp2f(fmaf(q1, kc.y, q0 * kc.x));
        const float e5 = __builtin_amdgcn_exp2f(fmaf(q1, kc.w, q0 * kc.z));
        const float e6 = __builtin_amdgcn_exp2f(fmaf(q1, kd.y, q0 * kd.x));
        const float e7 = __builtin_amdgcn_exp2f(fmaf(q1, kd.w, q0 * kd.z));

        uint4v ep;
        ep[0] = pkbf(e0, e1); ep[1] = pkbf(e2, e3);
        ep[2] = pkbf(e4, e5); ep[3] = pkbf(e6, e7);
        const short8 eb = __builtin_bit_cast(short8, ep);

        acc  = __builtin_amdgcn_mfma_f32_16x16x32_bf16(yh,   eb, acc,  0, 0, 0);
        acc  = __builtin_amdgcn_mfma_f32_16x16x32_bf16(yl,   eb, acc,  0, 0, 0);
        acc2 = __builtin_amdgcn_mfma_f32_16x16x32_bf16(ones, eb, acc2, 0, 0, 0);

        // rotate
        yh = yhn; yl = yln;
        ka = kan; kb = kbn; kc = kcn; kd = kdn;
    }

    // Flush: lane holds numer[i0+m][quad*4+r] = acc[r]; dsum(i0+m) = acc2[*]
    float* nrow = numer + (size_t)(i0 + m) * NCLS + quad * 4;
#pragma unroll
    for (int r = 0; r < 4; ++r)
        atomicAdd(nrow + r, acc[r]);
    if (quad == 0)
        atomicAdd(denom + i0 + m, acc2[0]);
}

// ---------------------------------------------------------------------------
// Kernel 3: finalize — divide numerators by softmax denominator.
// ---------------------------------------------------------------------------
__global__ __launch_bounds__(256) void finalize_kernel(
    const float* __restrict__ numer, const float* __restrict__ denom,
    float* __restrict__ out)
{
    const int idx = blockIdx.x * 256 + threadIdx.x;   // < NT*NCLS
    out[idx] = numer[idx] / denom[idx >> 4];
}

// ---------------------------------------------------------------------------
extern "C" void kernel_launch(void* const* d_in, const int* in_sizes, int n_in,
                              void* d_out, int out_size, void* d_ws, size_t ws_size,
                              hipStream_t stream)
{
    const float* xtr = (const float*)d_in[0];   // [16384][512]
    const float* ytr = (const float*)d_in[1];   // [16384][16]
    const float* xt  = (const float*)d_in[2];   // [8192][512]
    const float* A   = (const float*)d_in[3];   // [512][2]
    float* out = (float*)d_out;                 // [8192][16]

    float* kq    = (float*)d_ws;                       // 49152 floats
    float* numer = kq + WS_KQ_F;                       // 131072 floats
    float* denom = numer + WS_NUMER_F;                 // 8192 floats
    short* yfh   = (short*)(denom + WS_DENOM_F);       // 262144 shorts (512 KB)
    short* yfl   = yfh + NSTEPS * 64 * 8;              // 262144 shorts (512 KB)

    prep_kernel<<<PROJ_BLOCKS + PREP_BLOCKS, 256, 0, stream>>>(
        xtr, xt, A, ytr, kq, yfh, yfl, numer);
    simmain_kernel<<<dim3(NT / 64, JS), 256, 0, stream>>>(
        kq, yfh, yfl, numer, denom);
    finalize_kernel<<<(NT * NCLS) / 256, 256, 0, stream>>>(numer, denom, out);
}